// Round 4
// baseline (1473.490 us; speedup 1.0000x reference)
//
#include <hip/hip_runtime.h>

#define D_IN 256
#define D_OUT 128
#define ALPHA 0.2f
#define RB 128          // src nodes per bucket
#define NBMAX 800
#define CH 4096         // edges per k_bfill block

typedef __attribute__((ext_vector_type(8))) short bf16x8;
typedef __attribute__((ext_vector_type(4))) float f32x4;

__device__ inline unsigned short f2bf(float f) {
    unsigned int u = __float_as_uint(f);
    return (unsigned short)((u + 0x7FFFu + ((u >> 16) & 1u)) >> 16);
}
__device__ inline float bf2f(unsigned short u) {
    return __uint_as_float(((unsigned int)u) << 16);
}
__device__ inline void lds_fadd(float* p, float v) {
    __hip_atomic_fetch_add(p, v, __ATOMIC_RELAXED, __HIP_MEMORY_SCOPE_WORKGROUP);
}

// ---------------- x fp32 -> xb bf16 ----------------
__global__ __launch_bounds__(256) void k_xb(const float* __restrict__ x,
                                            unsigned short* __restrict__ xb,
                                            size_t total8) {
    for (size_t i = (size_t)blockIdx.x * blockDim.x + threadIdx.x; i < total8;
         i += (size_t)gridDim.x * blockDim.x) {
        float4 a = ((const float4*)x)[2 * i];
        float4 b = ((const float4*)x)[2 * i + 1];
        bf16x8 v;
        v[0] = (short)f2bf(a.x); v[1] = (short)f2bf(a.y);
        v[2] = (short)f2bf(a.z); v[3] = (short)f2bf(a.w);
        v[4] = (short)f2bf(b.x); v[5] = (short)f2bf(b.y);
        v[6] = (short)f2bf(b.z); v[7] = (short)f2bf(b.w);
        ((bf16x8*)xb)[i] = v;
    }
}

// ---------------- W -> WTb (transposed bf16) ----------------
__global__ __launch_bounds__(256) void k_wt(const float* __restrict__ W,
                                            unsigned short* __restrict__ WTb) {
    const int ncol = blockIdx.x;
    const int k = threadIdx.x;
    WTb[(size_t)ncol * 256 + k] = f2bf(W[(size_t)k * 128 + ncol]);
}

// ---------------- GEMM: hb = xb @ W, MFMA 16x16x32 ----------------
__global__ __launch_bounds__(256) void k_gemm(const unsigned short* __restrict__ xb,
                                              const unsigned short* __restrict__ WTb,
                                              unsigned short* __restrict__ hb, int n) {
    const int t = threadIdx.x;
    const int l = t & 63;
    const int w = t >> 6;
    const int wr = w >> 1, wc = w & 1;
    const int row0 = blockIdx.x * 128 + wr * 64;
    const int col0 = wc * 64;
    const int lr = l & 15;
    const int lk8 = (l >> 4) * 8;

    f32x4 acc[4][4] = {};

    const unsigned short* ap[4];
    #pragma unroll
    for (int mi = 0; mi < 4; ++mi) {
        int r = row0 + mi * 16 + lr;
        if (r > n - 1) r = n - 1;
        ap[mi] = xb + (size_t)r * D_IN + lk8;
    }
    const unsigned short* bp[4];
    #pragma unroll
    for (int ni = 0; ni < 4; ++ni)
        bp[ni] = WTb + (size_t)(col0 + ni * 16 + lr) * 256 + lk8;

    #pragma unroll
    for (int k0 = 0; k0 < D_IN; k0 += 32) {
        bf16x8 af[4], bfr[4];
        #pragma unroll
        for (int mi = 0; mi < 4; ++mi) af[mi]  = *(const bf16x8*)(ap[mi] + k0);
        #pragma unroll
        for (int ni = 0; ni < 4; ++ni) bfr[ni] = *(const bf16x8*)(bp[ni] + k0);
        #pragma unroll
        for (int mi = 0; mi < 4; ++mi)
            #pragma unroll
            for (int ni = 0; ni < 4; ++ni)
                acc[mi][ni] = __builtin_amdgcn_mfma_f32_16x16x32_bf16(
                    af[mi], bfr[ni], acc[mi][ni], 0, 0, 0);
    }

    const int rq = (l >> 4) * 4;
    #pragma unroll
    for (int mi = 0; mi < 4; ++mi) {
        #pragma unroll
        for (int q = 0; q < 4; ++q) {
            int r = row0 + mi * 16 + rq + q;
            if (r < n) {
                #pragma unroll
                for (int ni = 0; ni < 4; ++ni)
                    hb[(size_t)r * D_OUT + col0 + ni * 16 + lr] =
                        f2bf(acc[mi][ni][q]);
            }
        }
    }
}

// ---------------- f_src / f_dst ----------------
__global__ __launch_bounds__(256) void k_f(const unsigned short* __restrict__ hb,
                                           const float* __restrict__ a,
                                           float* __restrict__ f_src,
                                           float* __restrict__ f_dst, int n) {
    const int node = blockIdx.x * 4 + (threadIdx.x >> 6);
    const int lane = threadIdx.x & 63;
    if (node >= n) return;
    ushort2 hv = *(const ushort2*)&hb[(size_t)node * D_OUT + lane * 2];
    float h0 = bf2f(hv.x), h1 = bf2f(hv.y);
    float fs = h0 * a[lane * 2]         + h1 * a[lane * 2 + 1];
    float fd = h0 * a[D_OUT + lane * 2] + h1 * a[D_OUT + lane * 2 + 1];
    #pragma unroll
    for (int off = 32; off > 0; off >>= 1) {
        fs += __shfl_down(fs, off);
        fd += __shfl_down(fd, off);
    }
    if (lane == 0) {
        f_src[node] = fs;
        f_dst[node] = fd;
    }
}

// ---------------- bucket histogram (LDS-privatized) ----------------
__global__ __launch_bounds__(256) void k_bhist(const int* __restrict__ src,
                                               int* __restrict__ ghist, int E, int nb) {
    __shared__ int lh[NBMAX];
    for (int i = threadIdx.x; i < nb; i += 256) lh[i] = 0;
    __syncthreads();
    for (int e = blockIdx.x * 256 + threadIdx.x; e < E; e += gridDim.x * 256)
        atomicAdd(&lh[src[e] >> 7], 1);
    __syncthreads();
    for (int i = threadIdx.x; i < nb; i += 256) {
        int c = lh[i];
        if (c) atomicAdd(&ghist[i], c);
    }
}

// ---------------- bucket scan: gbase (exclusive) + gcur ----------------
__global__ __launch_bounds__(256) void k_bscan(const int* __restrict__ ghist,
                                               int* __restrict__ gbase,
                                               int* __restrict__ gcur, int nb, int E) {
    const int t = threadIdx.x;
    const int i0 = t * 4;
    int v[4];
    int tot = 0;
    #pragma unroll
    for (int j = 0; j < 4; ++j) {
        int i = i0 + j;
        v[j] = (i < nb) ? ghist[i] : 0;
        tot += v[j];
    }
    __shared__ int sc[256];
    sc[t] = tot;
    __syncthreads();
    #pragma unroll
    for (int off = 1; off < 256; off <<= 1) {
        int add = (t >= off) ? sc[t - off] : 0;
        __syncthreads();
        sc[t] += add;
        __syncthreads();
    }
    int base = sc[t] - tot;
    int run = 0;
    #pragma unroll
    for (int j = 0; j < 4; ++j) {
        int i = i0 + j;
        if (i < nb) {
            gbase[i] = base + run;
            gcur[i]  = base + run;
        }
        run += v[j];
    }
    if (t == 255) gbase[nb] = E;
}

// ---------------- bucket fill: packed keys, block-privatized ----------------
__global__ __launch_bounds__(256) void k_bfill(const int* __restrict__ src,
                                               const int* __restrict__ dst,
                                               int* __restrict__ gcur,
                                               int* __restrict__ gkeys, int E, int nb) {
    __shared__ int cnt[NBMAX];
    __shared__ int bas[NBMAX];
    const int t = threadIdx.x;
    const int e0 = blockIdx.x * CH;
    const int e1 = min(e0 + CH, E);
    for (int i = t; i < nb; i += 256) cnt[i] = 0;
    __syncthreads();
    for (int e = e0 + t; e < e1; e += 256) atomicAdd(&cnt[src[e] >> 7], 1);
    __syncthreads();
    for (int b = t; b < nb; b += 256) {
        int c = cnt[b];
        bas[b] = c ? atomicAdd(&gcur[b], c) : 0;
        cnt[b] = 0;
    }
    __syncthreads();
    for (int e = e0 + t; e < e1; e += 256) {
        int s = src[e], d = dst[e];
        int b = s >> 7;
        int r = atomicAdd(&cnt[b], 1);
        gkeys[bas[b] + r] = ((s & (RB - 1)) << 17) | d;
    }
}

// ---------------- fused aggregation: block per bucket, LDS accumulators ----------------
__global__ __launch_bounds__(256) void k_bagg(const unsigned short* __restrict__ hb,
                                              const float* __restrict__ f_src,
                                              const float* __restrict__ f_dst,
                                              const int* __restrict__ gbase,
                                              const int* __restrict__ gkeys,
                                              float* __restrict__ out, int n) {
    __shared__ float acc[RB * D_OUT];   // 64 KB
    __shared__ float rs[RB];
    __shared__ float fsl[RB];
    const int t = threadIdx.x;
    const int b = blockIdx.x;
    const int s0 = b * RB;
    const int nn = min(RB, n - s0);
    for (int i = t; i < RB * D_OUT; i += 256) acc[i] = 0.f;
    for (int i = t; i < RB; i += 256) {
        rs[i] = 0.f;
        fsl[i] = (i < nn) ? f_src[s0 + i] : 0.f;
    }
    __syncthreads();

    const int beg = gbase[b], end = gbase[b + 1];
    const int lane = t & 63, wid = t >> 6;

    int e = beg + wid;
    // 4-deep software pipeline (4 keys + 4 f_dst + 4 gathers in flight)
    while (e + 12 < end) {
        int k0 = gkeys[e], k1 = gkeys[e + 4], k2 = gkeys[e + 8], k3 = gkeys[e + 12];
        int d0 = k0 & 0x1FFFF, d1 = k1 & 0x1FFFF, d2 = k2 & 0x1FFFF, d3 = k3 & 0x1FFFF;
        int l0 = k0 >> 17, l1 = k1 >> 17, l2 = k2 >> 17, l3 = k3 >> 17;
        float fd0 = f_dst[d0], fd1 = f_dst[d1], fd2 = f_dst[d2], fd3 = f_dst[d3];
        ushort2 h0 = *(const ushort2*)&hb[(size_t)d0 * D_OUT + lane * 2];
        ushort2 h1 = *(const ushort2*)&hb[(size_t)d1 * D_OUT + lane * 2];
        ushort2 h2 = *(const ushort2*)&hb[(size_t)d2 * D_OUT + lane * 2];
        ushort2 h3 = *(const ushort2*)&hb[(size_t)d3 * D_OUT + lane * 2];
        float t0 = fsl[l0] + fd0, t1 = fsl[l1] + fd1, t2 = fsl[l2] + fd2, t3 = fsl[l3] + fd3;
        float w0 = __expf(-((t0 > 0.f) ? t0 : ALPHA * t0));
        float w1 = __expf(-((t1 > 0.f) ? t1 : ALPHA * t1));
        float w2 = __expf(-((t2 > 0.f) ? t2 : ALPHA * t2));
        float w3 = __expf(-((t3 > 0.f) ? t3 : ALPHA * t3));
        float* a0 = &acc[l0 * D_OUT + lane * 2];
        float* a1 = &acc[l1 * D_OUT + lane * 2];
        float* a2 = &acc[l2 * D_OUT + lane * 2];
        float* a3 = &acc[l3 * D_OUT + lane * 2];
        lds_fadd(a0,     w0 * bf2f(h0.x)); lds_fadd(a0 + 1, w0 * bf2f(h0.y));
        lds_fadd(a1,     w1 * bf2f(h1.x)); lds_fadd(a1 + 1, w1 * bf2f(h1.y));
        lds_fadd(a2,     w2 * bf2f(h2.x)); lds_fadd(a2 + 1, w2 * bf2f(h2.y));
        lds_fadd(a3,     w3 * bf2f(h3.x)); lds_fadd(a3 + 1, w3 * bf2f(h3.y));
        if (lane == 0) {
            lds_fadd(&rs[l0], w0); lds_fadd(&rs[l1], w1);
            lds_fadd(&rs[l2], w2); lds_fadd(&rs[l3], w3);
        }
        e += 16;
    }
    while (e < end) {
        int k0 = gkeys[e];
        int d0 = k0 & 0x1FFFF, l0 = k0 >> 17;
        float t0 = fsl[l0] + f_dst[d0];
        float w0 = __expf(-((t0 > 0.f) ? t0 : ALPHA * t0));
        ushort2 h0 = *(const ushort2*)&hb[(size_t)d0 * D_OUT + lane * 2];
        float* a0 = &acc[l0 * D_OUT + lane * 2];
        lds_fadd(a0, w0 * bf2f(h0.x));
        lds_fadd(a0 + 1, w0 * bf2f(h0.y));
        if (lane == 0) lds_fadd(&rs[l0], w0);
        e += 4;
    }
    __syncthreads();

    for (int ni = wid; ni < nn; ni += 4) {
        float inv = 1.f / rs[ni];
        float v0 = acc[ni * D_OUT + lane * 2] * inv;
        float v1 = acc[ni * D_OUT + lane * 2 + 1] * inv;
        v0 = (v0 > 0.f) ? v0 : (__expf(v0) - 1.f);
        v1 = (v1 > 0.f) ? v1 : (__expf(v1) - 1.f);
        *(float2*)&out[(size_t)(s0 + ni) * D_OUT + lane * 2] = make_float2(v0, v1);
    }
}

extern "C" void kernel_launch(void* const* d_in, const int* in_sizes, int n_in,
                              void* d_out, int out_size, void* d_ws, size_t ws_size,
                              hipStream_t stream) {
    const float* x    = (const float*)d_in[0];
    const int*   edge = (const int*)d_in[1];   // JAX no-x64: int64 -> int32
    const float* W    = (const float*)d_in[2];
    const float* a    = (const float*)d_in[3];
    float* out = (float*)d_out;

    const int n = in_sizes[0] / D_IN;
    const int E = in_sizes[1] / 2;
    const int* src = edge;
    const int* dst = edge + E;
    const int nb = (n + RB - 1) / RB;

    char* p = (char*)d_ws;
    unsigned short* hb  = (unsigned short*)p; p += (size_t)n * D_OUT * sizeof(unsigned short);
    unsigned short* xb  = (unsigned short*)p; p += (size_t)n * D_IN * sizeof(unsigned short);
    unsigned short* WTb = (unsigned short*)p; p += (size_t)D_OUT * D_IN * sizeof(unsigned short);
    float* f_src = (float*)p;  p += (size_t)n * sizeof(float);
    float* f_dst = (float*)p;  p += (size_t)n * sizeof(float);
    int* ghist   = (int*)p;    p += (size_t)nb * sizeof(int);
    int* gbase   = (int*)p;    p += (size_t)(nb + 1) * sizeof(int);
    int* gcur    = (int*)p;    p += (size_t)nb * sizeof(int);
    int* gkeys   = (int*)p;    p += (size_t)E * sizeof(int);

    const int gemm_blocks = (n + 127) / 128;
    const size_t total8 = (size_t)n * D_IN / 8;

    k_xb<<<2048, 256, 0, stream>>>(x, xb, total8);
    k_wt<<<D_OUT, 256, 0, stream>>>(W, WTb);
    k_gemm<<<gemm_blocks, 256, 0, stream>>>(xb, WTb, hb, n);
    k_f<<<(n + 3) / 4, 256, 0, stream>>>(hb, a, f_src, f_dst, n);

    hipMemsetAsync(ghist, 0, (size_t)nb * sizeof(int), stream);
    k_bhist<<<256, 256, 0, stream>>>(src, ghist, E, nb);
    k_bscan<<<1, 256, 0, stream>>>(ghist, gbase, gcur, nb, E);
    k_bfill<<<(E + CH - 1) / CH, 256, 0, stream>>>(src, dst, gcur, gkeys, E, nb);
    k_bagg<<<nb, 256, 0, stream>>>(hb, f_src, f_dst, gbase, gkeys, out, n);
}

// Round 5
// 218.448 us; speedup vs baseline: 6.7453x; 6.7453x over previous
//
#include <hip/hip_runtime.h>

#define D_IN 256
#define D_OUT 128
#define ALPHA 0.2f
#define RB 128          // src nodes per bucket
#define NBMAX 800
#define CH 8192         // edges per k_bfill block
#define CAP 4608        // max edges handled via LDS per bucket (mean 2046, ~40 sigma)

typedef __attribute__((ext_vector_type(8))) short bf16x8;
typedef __attribute__((ext_vector_type(4))) float f32x4;

__device__ inline unsigned short f2bf(float f) {
    unsigned int u = __float_as_uint(f);
    return (unsigned short)((u + 0x7FFFu + ((u >> 16) & 1u)) >> 16);
}
__device__ inline float bf2f(unsigned short u) {
    return __uint_as_float(((unsigned int)u) << 16);
}

// ---------------- x fp32 -> xb bf16 ----------------
__global__ __launch_bounds__(256) void k_xb(const float* __restrict__ x,
                                            unsigned short* __restrict__ xb,
                                            size_t total8) {
    for (size_t i = (size_t)blockIdx.x * blockDim.x + threadIdx.x; i < total8;
         i += (size_t)gridDim.x * blockDim.x) {
        float4 a = ((const float4*)x)[2 * i];
        float4 b = ((const float4*)x)[2 * i + 1];
        bf16x8 v;
        v[0] = (short)f2bf(a.x); v[1] = (short)f2bf(a.y);
        v[2] = (short)f2bf(a.z); v[3] = (short)f2bf(a.w);
        v[4] = (short)f2bf(b.x); v[5] = (short)f2bf(b.y);
        v[6] = (short)f2bf(b.z); v[7] = (short)f2bf(b.w);
        ((bf16x8*)xb)[i] = v;
    }
}

// ---------------- W -> WTb (transposed bf16) ----------------
__global__ __launch_bounds__(256) void k_wt(const float* __restrict__ W,
                                            unsigned short* __restrict__ WTb) {
    const int ncol = blockIdx.x;
    const int k = threadIdx.x;
    WTb[(size_t)ncol * 256 + k] = f2bf(W[(size_t)k * 128 + ncol]);
}

// ---------------- GEMM: hb = xb @ W, MFMA 16x16x32 ----------------
__global__ __launch_bounds__(256) void k_gemm(const unsigned short* __restrict__ xb,
                                              const unsigned short* __restrict__ WTb,
                                              unsigned short* __restrict__ hb, int n) {
    const int t = threadIdx.x;
    const int l = t & 63;
    const int w = t >> 6;
    const int wr = w >> 1, wc = w & 1;
    const int row0 = blockIdx.x * 128 + wr * 64;
    const int col0 = wc * 64;
    const int lr = l & 15;
    const int lk8 = (l >> 4) * 8;

    f32x4 acc[4][4] = {};

    const unsigned short* ap[4];
    #pragma unroll
    for (int mi = 0; mi < 4; ++mi) {
        int r = row0 + mi * 16 + lr;
        if (r > n - 1) r = n - 1;
        ap[mi] = xb + (size_t)r * D_IN + lk8;
    }
    const unsigned short* bp[4];
    #pragma unroll
    for (int ni = 0; ni < 4; ++ni)
        bp[ni] = WTb + (size_t)(col0 + ni * 16 + lr) * 256 + lk8;

    #pragma unroll
    for (int k0 = 0; k0 < D_IN; k0 += 32) {
        bf16x8 af[4], bfr[4];
        #pragma unroll
        for (int mi = 0; mi < 4; ++mi) af[mi]  = *(const bf16x8*)(ap[mi] + k0);
        #pragma unroll
        for (int ni = 0; ni < 4; ++ni) bfr[ni] = *(const bf16x8*)(bp[ni] + k0);
        #pragma unroll
        for (int mi = 0; mi < 4; ++mi)
            #pragma unroll
            for (int ni = 0; ni < 4; ++ni)
                acc[mi][ni] = __builtin_amdgcn_mfma_f32_16x16x32_bf16(
                    af[mi], bfr[ni], acc[mi][ni], 0, 0, 0);
    }

    const int rq = (l >> 4) * 4;
    #pragma unroll
    for (int mi = 0; mi < 4; ++mi) {
        #pragma unroll
        for (int q = 0; q < 4; ++q) {
            int r = row0 + mi * 16 + rq + q;
            if (r < n) {
                #pragma unroll
                for (int ni = 0; ni < 4; ++ni)
                    hb[(size_t)r * D_OUT + col0 + ni * 16 + lr] =
                        f2bf(acc[mi][ni][q]);
            }
        }
    }
}

// ---------------- f_src / f_dst ----------------
__global__ __launch_bounds__(256) void k_f(const unsigned short* __restrict__ hb,
                                           const float* __restrict__ a,
                                           float* __restrict__ f_src,
                                           float* __restrict__ f_dst, int n) {
    const int node = blockIdx.x * 4 + (threadIdx.x >> 6);
    const int lane = threadIdx.x & 63;
    if (node >= n) return;
    ushort2 hv = *(const ushort2*)&hb[(size_t)node * D_OUT + lane * 2];
    float h0 = bf2f(hv.x), h1 = bf2f(hv.y);
    float fs = h0 * a[lane * 2]         + h1 * a[lane * 2 + 1];
    float fd = h0 * a[D_OUT + lane * 2] + h1 * a[D_OUT + lane * 2 + 1];
    #pragma unroll
    for (int off = 32; off > 0; off >>= 1) {
        fs += __shfl_down(fs, off);
        fd += __shfl_down(fd, off);
    }
    if (lane == 0) {
        f_src[node] = fs;
        f_dst[node] = fd;
    }
}

// ---------------- bucket histogram (LDS-privatized, int atomics) ----------------
__global__ __launch_bounds__(256) void k_bhist(const int* __restrict__ src,
                                               int* __restrict__ ghist, int E, int nb) {
    __shared__ int lh[NBMAX];
    for (int i = threadIdx.x; i < nb; i += 256) lh[i] = 0;
    __syncthreads();
    for (int e = blockIdx.x * 256 + threadIdx.x; e < E; e += gridDim.x * 256)
        atomicAdd(&lh[src[e] >> 7], 1);
    __syncthreads();
    for (int i = threadIdx.x; i < nb; i += 256) {
        int c = lh[i];
        if (c) atomicAdd(&ghist[i], c);
    }
}

// ---------------- bucket scan ----------------
__global__ __launch_bounds__(256) void k_bscan(const int* __restrict__ ghist,
                                               int* __restrict__ gbase,
                                               int* __restrict__ gcur, int nb, int E) {
    const int t = threadIdx.x;
    const int i0 = t * 4;
    int v[4];
    int tot = 0;
    #pragma unroll
    for (int j = 0; j < 4; ++j) {
        int i = i0 + j;
        v[j] = (i < nb) ? ghist[i] : 0;
        tot += v[j];
    }
    __shared__ int sc[256];
    sc[t] = tot;
    __syncthreads();
    #pragma unroll
    for (int off = 1; off < 256; off <<= 1) {
        int add = (t >= off) ? sc[t - off] : 0;
        __syncthreads();
        sc[t] += add;
        __syncthreads();
    }
    int base = sc[t] - tot;
    int run = 0;
    #pragma unroll
    for (int j = 0; j < 4; ++j) {
        int i = i0 + j;
        if (i < nb) {
            gbase[i] = base + run;
            gcur[i]  = base + run;
        }
        run += v[j];
    }
    if (t == 255) gbase[nb] = E;
}

// ---------------- bucket fill: packed keys (lsrc<<17 | dst) ----------------
__global__ __launch_bounds__(256) void k_bfill(const int* __restrict__ src,
                                               const int* __restrict__ dst,
                                               int* __restrict__ gcur,
                                               int* __restrict__ gkeys, int E, int nb) {
    __shared__ int cnt[NBMAX];
    __shared__ int bas[NBMAX];
    const int t = threadIdx.x;
    const int e0 = blockIdx.x * CH;
    const int e1 = min(e0 + CH, E);
    for (int i = t; i < nb; i += 256) cnt[i] = 0;
    __syncthreads();
    for (int e = e0 + t; e < e1; e += 256) atomicAdd(&cnt[src[e] >> 7], 1);
    __syncthreads();
    for (int b = t; b < nb; b += 256) {
        int c = cnt[b];
        bas[b] = c ? atomicAdd(&gcur[b], c) : 0;
        cnt[b] = 0;
    }
    __syncthreads();
    for (int e = e0 + t; e < e1; e += 256) {
        int s = src[e], d = dst[e];
        int b = s >> 7;
        int r = atomicAdd(&cnt[b], 1);
        gkeys[bas[b] + r] = ((s & (RB - 1)) << 17) | d;
    }
}

// ---------------- aggregation: block/bucket, LDS per-node lists, reg accum ----------------
__global__ __launch_bounds__(256) void k_bagg(const unsigned short* __restrict__ hb,
                                              const float* __restrict__ f_src,
                                              const float* __restrict__ f_dst,
                                              const int* __restrict__ gbase,
                                              const int* __restrict__ gkeys,
                                              float* __restrict__ out, int n) {
    __shared__ int2 sdw[CAP];        // (dst, weight-bits), grouped by local src
    __shared__ int nbase[RB];
    __shared__ int ncnt[RB];
    __shared__ int ncur[RB];
    __shared__ float fsl[RB];
    __shared__ int sc[RB];
    const int t = threadIdx.x;
    const int b = blockIdx.x;
    const int s0 = b * RB;
    const int nn = min(RB, n - s0);
    const int beg = gbase[b], end = gbase[b + 1];
    const int m = min(end - beg, CAP);

    for (int i = t; i < RB; i += 256) {
        ncnt[i] = 0;
        fsl[i] = (i < nn) ? f_src[s0 + i] : 0.f;
    }
    __syncthreads();

    // pass 1: per-node histogram (native int LDS atomics)
    for (int i = t; i < m; i += 256)
        atomicAdd(&ncnt[gkeys[beg + i] >> 17], 1);
    __syncthreads();

    // scan of 128 counters (Hillis-Steele in LDS; all threads hit barriers)
    if (t < RB) sc[t] = ncnt[t];
    __syncthreads();
    for (int off = 1; off < RB; off <<= 1) {
        int v = 0;
        if (t < RB && t >= off) v = sc[t - off];
        __syncthreads();
        if (t < RB) sc[t] += v;
        __syncthreads();
    }
    if (t < RB) {
        nbase[t] = sc[t] - ncnt[t];
        ncur[t]  = sc[t] - ncnt[t];
    }
    __syncthreads();

    // pass 2: scatter (d, w) grouped by local src; weights computed lane-parallel
    for (int i = t; i < m; i += 256) {
        int k = gkeys[beg + i];
        int d = k & 0x1FFFF, ls = k >> 17;
        float tmp = fsl[ls] + f_dst[d];
        float w = __expf(-((tmp > 0.f) ? tmp : ALPHA * tmp));
        int pos = atomicAdd(&ncur[ls], 1);
        sdw[pos] = make_int2(d, __float_as_int(w));
    }
    __syncthreads();

    // pass 3: wave-per-node register accumulation
    const int lane = t & 63, wid = t >> 6;
    for (int ni = wid; ni < nn; ni += 4) {
        const int jb = nbase[ni];
        const int je = jb + ncnt[ni];
        float acc0 = 0.f, acc1 = 0.f, rowsum = 0.f;
        #pragma unroll 4
        for (int j = jb; j < je; ++j) {
            int2 dw = sdw[j];                    // uniform address -> broadcast
            float w = __int_as_float(dw.y);
            ushort2 hv = *(const ushort2*)&hb[(size_t)dw.x * D_OUT + lane * 2];
            rowsum += w;
            acc0 = fmaf(w, bf2f(hv.x), acc0);
            acc1 = fmaf(w, bf2f(hv.y), acc1);
        }
        // overflow fallback (never triggers for this input; zero cost when m == end-beg)
        for (int j = beg + m; j < end; ++j) {
            int k = gkeys[j];
            if ((k >> 17) == ni) {
                int d = k & 0x1FFFF;
                float tmp = fsl[ni] + f_dst[d];
                float w = __expf(-((tmp > 0.f) ? tmp : ALPHA * tmp));
                ushort2 hv = *(const ushort2*)&hb[(size_t)d * D_OUT + lane * 2];
                rowsum += w;
                acc0 = fmaf(w, bf2f(hv.x), acc0);
                acc1 = fmaf(w, bf2f(hv.y), acc1);
            }
        }
        float inv = 1.f / rowsum;
        acc0 *= inv;
        acc1 *= inv;
        acc0 = (acc0 > 0.f) ? acc0 : (__expf(acc0) - 1.f);
        acc1 = (acc1 > 0.f) ? acc1 : (__expf(acc1) - 1.f);
        *(float2*)&out[(size_t)(s0 + ni) * D_OUT + lane * 2] = make_float2(acc0, acc1);
    }
}

extern "C" void kernel_launch(void* const* d_in, const int* in_sizes, int n_in,
                              void* d_out, int out_size, void* d_ws, size_t ws_size,
                              hipStream_t stream) {
    const float* x    = (const float*)d_in[0];
    const int*   edge = (const int*)d_in[1];   // JAX no-x64: int64 -> int32
    const float* W    = (const float*)d_in[2];
    const float* a    = (const float*)d_in[3];
    float* out = (float*)d_out;

    const int n = in_sizes[0] / D_IN;
    const int E = in_sizes[1] / 2;
    const int* src = edge;
    const int* dst = edge + E;
    const int nb = (n + RB - 1) / RB;

    char* p = (char*)d_ws;
    unsigned short* hb  = (unsigned short*)p; p += (size_t)n * D_OUT * sizeof(unsigned short);
    unsigned short* xb  = (unsigned short*)p; p += (size_t)n * D_IN * sizeof(unsigned short);
    unsigned short* WTb = (unsigned short*)p; p += (size_t)D_OUT * D_IN * sizeof(unsigned short);
    float* f_src = (float*)p;  p += (size_t)n * sizeof(float);
    float* f_dst = (float*)p;  p += (size_t)n * sizeof(float);
    int* ghist   = (int*)p;    p += (size_t)nb * sizeof(int);
    int* gbase   = (int*)p;    p += (size_t)(nb + 1) * sizeof(int);
    int* gcur    = (int*)p;    p += (size_t)nb * sizeof(int);
    int* gkeys   = (int*)p;    p += (size_t)E * sizeof(int);

    const int gemm_blocks = (n + 127) / 128;
    const size_t total8 = (size_t)n * D_IN / 8;

    k_xb<<<2048, 256, 0, stream>>>(x, xb, total8);
    k_wt<<<D_OUT, 256, 0, stream>>>(W, WTb);
    k_gemm<<<gemm_blocks, 256, 0, stream>>>(xb, WTb, hb, n);
    k_f<<<(n + 3) / 4, 256, 0, stream>>>(hb, a, f_src, f_dst, n);

    hipMemsetAsync(ghist, 0, (size_t)nb * sizeof(int), stream);
    k_bhist<<<256, 256, 0, stream>>>(src, ghist, E, nb);
    k_bscan<<<1, 256, 0, stream>>>(ghist, gbase, gcur, nb, E);
    k_bfill<<<(E + CH - 1) / CH, 256, 0, stream>>>(src, dst, gcur, gkeys, E, nb);
    k_bagg<<<nb, 256, 0, stream>>>(hb, f_src, f_dst, gbase, gkeys, out, n);
}

// Round 6
// 204.381 us; speedup vs baseline: 7.2095x; 1.0688x over previous
//
#include <hip/hip_runtime.h>

#define D_IN 256
#define D_OUT 128
#define ALPHA 0.2f
#define RB 64           // src nodes per bucket
#define RBSH 6
#define NBMAX 1600
#define CH 8192         // edges per k_bfill block
#define CAP 2304        // max edges via LDS per bucket (mean 1023, ~40 sigma)

typedef __attribute__((ext_vector_type(8))) short bf16x8;
typedef __attribute__((ext_vector_type(4))) float f32x4;

__device__ inline unsigned short f2bf(float f) {
    unsigned int u = __float_as_uint(f);
    return (unsigned short)((u + 0x7FFFu + ((u >> 16) & 1u)) >> 16);
}
__device__ inline float bf2f(unsigned short u) {
    return __uint_as_float(((unsigned int)u) << 16);
}

// ---------------- x fp32 -> xb bf16 ----------------
__global__ __launch_bounds__(256) void k_xb(const float* __restrict__ x,
                                            unsigned short* __restrict__ xb,
                                            size_t total8) {
    for (size_t i = (size_t)blockIdx.x * blockDim.x + threadIdx.x; i < total8;
         i += (size_t)gridDim.x * blockDim.x) {
        float4 a = ((const float4*)x)[2 * i];
        float4 b = ((const float4*)x)[2 * i + 1];
        bf16x8 v;
        v[0] = (short)f2bf(a.x); v[1] = (short)f2bf(a.y);
        v[2] = (short)f2bf(a.z); v[3] = (short)f2bf(a.w);
        v[4] = (short)f2bf(b.x); v[5] = (short)f2bf(b.y);
        v[6] = (short)f2bf(b.z); v[7] = (short)f2bf(b.w);
        ((bf16x8*)xb)[i] = v;
    }
}

// ---------------- W -> WTb (transposed bf16) ----------------
__global__ __launch_bounds__(256) void k_wt(const float* __restrict__ W,
                                            unsigned short* __restrict__ WTb) {
    const int ncol = blockIdx.x;
    const int k = threadIdx.x;
    WTb[(size_t)ncol * 256 + k] = f2bf(W[(size_t)k * 128 + ncol]);
}

// ---------------- GEMM: hb = xb @ W, MFMA 16x16x32 ----------------
__global__ __launch_bounds__(256) void k_gemm(const unsigned short* __restrict__ xb,
                                              const unsigned short* __restrict__ WTb,
                                              unsigned short* __restrict__ hb, int n) {
    const int t = threadIdx.x;
    const int l = t & 63;
    const int w = t >> 6;
    const int wr = w >> 1, wc = w & 1;
    const int row0 = blockIdx.x * 128 + wr * 64;
    const int col0 = wc * 64;
    const int lr = l & 15;
    const int lk8 = (l >> 4) * 8;

    f32x4 acc[4][4] = {};

    const unsigned short* ap[4];
    #pragma unroll
    for (int mi = 0; mi < 4; ++mi) {
        int r = row0 + mi * 16 + lr;
        if (r > n - 1) r = n - 1;
        ap[mi] = xb + (size_t)r * D_IN + lk8;
    }
    const unsigned short* bp[4];
    #pragma unroll
    for (int ni = 0; ni < 4; ++ni)
        bp[ni] = WTb + (size_t)(col0 + ni * 16 + lr) * 256 + lk8;

    #pragma unroll
    for (int k0 = 0; k0 < D_IN; k0 += 32) {
        bf16x8 af[4], bfr[4];
        #pragma unroll
        for (int mi = 0; mi < 4; ++mi) af[mi]  = *(const bf16x8*)(ap[mi] + k0);
        #pragma unroll
        for (int ni = 0; ni < 4; ++ni) bfr[ni] = *(const bf16x8*)(bp[ni] + k0);
        #pragma unroll
        for (int mi = 0; mi < 4; ++mi)
            #pragma unroll
            for (int ni = 0; ni < 4; ++ni)
                acc[mi][ni] = __builtin_amdgcn_mfma_f32_16x16x32_bf16(
                    af[mi], bfr[ni], acc[mi][ni], 0, 0, 0);
    }

    const int rq = (l >> 4) * 4;
    #pragma unroll
    for (int mi = 0; mi < 4; ++mi) {
        #pragma unroll
        for (int q = 0; q < 4; ++q) {
            int r = row0 + mi * 16 + rq + q;
            if (r < n) {
                #pragma unroll
                for (int ni = 0; ni < 4; ++ni)
                    hb[(size_t)r * D_OUT + col0 + ni * 16 + lr] =
                        f2bf(acc[mi][ni][q]);
            }
        }
    }
}

// ---------------- f_src / f_dst ----------------
__global__ __launch_bounds__(256) void k_f(const unsigned short* __restrict__ hb,
                                           const float* __restrict__ a,
                                           float* __restrict__ f_src,
                                           float* __restrict__ f_dst, int n) {
    const int node = blockIdx.x * 4 + (threadIdx.x >> 6);
    const int lane = threadIdx.x & 63;
    if (node >= n) return;
    ushort2 hv = *(const ushort2*)&hb[(size_t)node * D_OUT + lane * 2];
    float h0 = bf2f(hv.x), h1 = bf2f(hv.y);
    float fs = h0 * a[lane * 2]         + h1 * a[lane * 2 + 1];
    float fd = h0 * a[D_OUT + lane * 2] + h1 * a[D_OUT + lane * 2 + 1];
    #pragma unroll
    for (int off = 32; off > 0; off >>= 1) {
        fs += __shfl_down(fs, off);
        fd += __shfl_down(fd, off);
    }
    if (lane == 0) {
        f_src[node] = fs;
        f_dst[node] = fd;
    }
}

// ---------------- bucket histogram (LDS-privatized, int atomics) ----------------
__global__ __launch_bounds__(256) void k_bhist(const int* __restrict__ src,
                                               int* __restrict__ ghist, int E, int nb) {
    __shared__ int lh[NBMAX];
    for (int i = threadIdx.x; i < nb; i += 256) lh[i] = 0;
    __syncthreads();
    for (int e = blockIdx.x * 256 + threadIdx.x; e < E; e += gridDim.x * 256)
        atomicAdd(&lh[src[e] >> RBSH], 1);
    __syncthreads();
    for (int i = threadIdx.x; i < nb; i += 256) {
        int c = lh[i];
        if (c) atomicAdd(&ghist[i], c);
    }
}

// ---------------- bucket scan (nb <= 2048) ----------------
__global__ __launch_bounds__(256) void k_bscan(const int* __restrict__ ghist,
                                               int* __restrict__ gbase,
                                               int* __restrict__ gcur, int nb, int E) {
    const int t = threadIdx.x;
    const int i0 = t * 8;
    int v[8];
    int tot = 0;
    #pragma unroll
    for (int j = 0; j < 8; ++j) {
        int i = i0 + j;
        v[j] = (i < nb) ? ghist[i] : 0;
        tot += v[j];
    }
    __shared__ int sc[256];
    sc[t] = tot;
    __syncthreads();
    #pragma unroll
    for (int off = 1; off < 256; off <<= 1) {
        int add = (t >= off) ? sc[t - off] : 0;
        __syncthreads();
        sc[t] += add;
        __syncthreads();
    }
    int base = sc[t] - tot;
    int run = 0;
    #pragma unroll
    for (int j = 0; j < 8; ++j) {
        int i = i0 + j;
        if (i < nb) {
            gbase[i] = base + run;
            gcur[i]  = base + run;
        }
        run += v[j];
    }
    if (t == 255) gbase[nb] = E;
}

// ---------------- bucket fill: packed keys (lsrc<<17 | dst) ----------------
__global__ __launch_bounds__(256) void k_bfill(const int* __restrict__ src,
                                               const int* __restrict__ dst,
                                               int* __restrict__ gcur,
                                               int* __restrict__ gkeys, int E, int nb) {
    __shared__ int cnt[NBMAX];
    __shared__ int bas[NBMAX];
    const int t = threadIdx.x;
    const int e0 = blockIdx.x * CH;
    const int e1 = min(e0 + CH, E);
    for (int i = t; i < nb; i += 256) cnt[i] = 0;
    __syncthreads();
    for (int e = e0 + t; e < e1; e += 256) atomicAdd(&cnt[src[e] >> RBSH], 1);
    __syncthreads();
    for (int b = t; b < nb; b += 256) {
        int c = cnt[b];
        bas[b] = c ? atomicAdd(&gcur[b], c) : 0;
        cnt[b] = 0;
    }
    __syncthreads();
    for (int e = e0 + t; e < e1; e += 256) {
        int s = src[e], d = dst[e];
        int b = s >> RBSH;
        int r = atomicAdd(&cnt[b], 1);
        gkeys[bas[b] + r] = ((s & (RB - 1)) << 17) | d;
    }
}

// ---------------- aggregation: block/bucket, LDS per-node lists, reg accum ----------------
__global__ __launch_bounds__(256) void k_bagg(const unsigned short* __restrict__ hb,
                                              const float* __restrict__ f_src,
                                              const float* __restrict__ f_dst,
                                              const int* __restrict__ gbase,
                                              const int* __restrict__ gkeys,
                                              float* __restrict__ out, int n) {
    __shared__ int2 sdw[CAP];        // (dst, weight-bits), grouped by local src
    __shared__ int nbase[RB];
    __shared__ int ncnt[RB];
    __shared__ int ncur[RB];
    __shared__ float fsl[RB];
    __shared__ int sc[RB];
    const int t = threadIdx.x;
    const int b = blockIdx.x;
    const int s0 = b * RB;
    const int nn = min(RB, n - s0);
    const int beg = gbase[b], end = gbase[b + 1];
    const int m = min(end - beg, CAP);

    for (int i = t; i < RB; i += 256) {
        ncnt[i] = 0;
        fsl[i] = (i < nn) ? f_src[s0 + i] : 0.f;
    }
    __syncthreads();

    // pass 1: per-node histogram (native int LDS atomics)
    for (int i = t; i < m; i += 256)
        atomicAdd(&ncnt[gkeys[beg + i] >> 17], 1);
    __syncthreads();

    // scan of RB counters (Hillis-Steele in LDS; all threads hit barriers)
    if (t < RB) sc[t] = ncnt[t];
    __syncthreads();
    for (int off = 1; off < RB; off <<= 1) {
        int v = 0;
        if (t < RB && t >= off) v = sc[t - off];
        __syncthreads();
        if (t < RB) sc[t] += v;
        __syncthreads();
    }
    if (t < RB) {
        nbase[t] = sc[t] - ncnt[t];
        ncur[t]  = sc[t] - ncnt[t];
    }
    __syncthreads();

    // pass 2: scatter (d, w) grouped by local src; weights computed lane-parallel
    for (int i = t; i < m; i += 256) {
        int k = gkeys[beg + i];
        int d = k & 0x1FFFF, ls = k >> 17;
        float tmp = fsl[ls] + f_dst[d];
        float w = __expf(-((tmp > 0.f) ? tmp : ALPHA * tmp));
        int pos = atomicAdd(&ncur[ls], 1);
        sdw[pos] = make_int2(d, __float_as_int(w));
    }
    __syncthreads();

    // pass 3: wave-per-node register accumulation
    const int lane = t & 63, wid = t >> 6;
    for (int ni = wid; ni < nn; ni += 4) {
        const int jb = nbase[ni];
        const int je = jb + ncnt[ni];
        float acc0 = 0.f, acc1 = 0.f, rowsum = 0.f;
        #pragma unroll 4
        for (int j = jb; j < je; ++j) {
            int2 dw = sdw[j];                    // uniform address -> broadcast
            float w = __int_as_float(dw.y);
            ushort2 hv = *(const ushort2*)&hb[(size_t)dw.x * D_OUT + lane * 2];
            rowsum += w;
            acc0 = fmaf(w, bf2f(hv.x), acc0);
            acc1 = fmaf(w, bf2f(hv.y), acc1);
        }
        // overflow fallback (never triggers for this input; zero cost when m == end-beg)
        for (int j = beg + m; j < end; ++j) {
            int k = gkeys[j];
            if ((k >> 17) == ni) {
                int d = k & 0x1FFFF;
                float tmp = fsl[ni] + f_dst[d];
                float w = __expf(-((tmp > 0.f) ? tmp : ALPHA * tmp));
                ushort2 hv = *(const ushort2*)&hb[(size_t)d * D_OUT + lane * 2];
                rowsum += w;
                acc0 = fmaf(w, bf2f(hv.x), acc0);
                acc1 = fmaf(w, bf2f(hv.y), acc1);
            }
        }
        float inv = 1.f / rowsum;
        acc0 *= inv;
        acc1 *= inv;
        acc0 = (acc0 > 0.f) ? acc0 : (__expf(acc0) - 1.f);
        acc1 = (acc1 > 0.f) ? acc1 : (__expf(acc1) - 1.f);
        *(float2*)&out[(size_t)(s0 + ni) * D_OUT + lane * 2] = make_float2(acc0, acc1);
    }
}

extern "C" void kernel_launch(void* const* d_in, const int* in_sizes, int n_in,
                              void* d_out, int out_size, void* d_ws, size_t ws_size,
                              hipStream_t stream) {
    const float* x    = (const float*)d_in[0];
    const int*   edge = (const int*)d_in[1];   // JAX no-x64: int64 -> int32
    const float* W    = (const float*)d_in[2];
    const float* a    = (const float*)d_in[3];
    float* out = (float*)d_out;

    const int n = in_sizes[0] / D_IN;
    const int E = in_sizes[1] / 2;
    const int* src = edge;
    const int* dst = edge + E;
    const int nb = (n + RB - 1) / RB;

    char* p = (char*)d_ws;
    unsigned short* hb  = (unsigned short*)p; p += (size_t)n * D_OUT * sizeof(unsigned short);
    unsigned short* xb  = (unsigned short*)p; p += (size_t)n * D_IN * sizeof(unsigned short);
    unsigned short* WTb = (unsigned short*)p; p += (size_t)D_OUT * D_IN * sizeof(unsigned short);
    float* f_src = (float*)p;  p += (size_t)n * sizeof(float);
    float* f_dst = (float*)p;  p += (size_t)n * sizeof(float);
    int* ghist   = (int*)p;    p += (size_t)nb * sizeof(int);
    int* gbase   = (int*)p;    p += (size_t)(nb + 1) * sizeof(int);
    int* gcur    = (int*)p;    p += (size_t)nb * sizeof(int);
    int* gkeys   = (int*)p;    p += (size_t)E * sizeof(int);

    const int gemm_blocks = (n + 127) / 128;
    const size_t total8 = (size_t)n * D_IN / 8;

    k_xb<<<2048, 256, 0, stream>>>(x, xb, total8);
    k_wt<<<D_OUT, 256, 0, stream>>>(W, WTb);
    k_gemm<<<gemm_blocks, 256, 0, stream>>>(xb, WTb, hb, n);
    k_f<<<(n + 3) / 4, 256, 0, stream>>>(hb, a, f_src, f_dst, n);

    hipMemsetAsync(ghist, 0, (size_t)nb * sizeof(int), stream);
    k_bhist<<<128, 256, 0, stream>>>(src, ghist, E, nb);
    k_bscan<<<1, 256, 0, stream>>>(ghist, gbase, gcur, nb, E);
    k_bfill<<<(E + CH - 1) / CH, 256, 0, stream>>>(src, dst, gcur, gkeys, E, nb);
    k_bagg<<<nb, 256, 0, stream>>>(hb, f_src, f_dst, gbase, gkeys, out, n);
}

// Round 7
// 177.136 us; speedup vs baseline: 8.3184x; 1.1538x over previous
//
#include <hip/hip_runtime.h>

#define D_IN 256
#define D_OUT 128
#define ALPHA 0.2f
#define RB 64           // src nodes per bucket
#define RBSH 6
#define NBMAX 1600
#define CH 8192         // edges per k_bfill block
#define CAP 2304        // max edges via LDS per bucket (mean 1023, ~40 sigma)
#define LDA 264         // padded LDS row stride in ushorts (528 B): conflict-free b128

typedef __attribute__((ext_vector_type(8))) short bf16x8;
typedef __attribute__((ext_vector_type(4))) float f32x4;

__device__ inline unsigned short f2bf(float f) {
    unsigned int u = __float_as_uint(f);
    return (unsigned short)((u + 0x7FFFu + ((u >> 16) & 1u)) >> 16);
}
__device__ inline float bf2f(unsigned short u) {
    return __uint_as_float(((unsigned int)u) << 16);
}

// ---------------- W -> WTb (transposed bf16) ----------------
__global__ __launch_bounds__(256) void k_wt(const float* __restrict__ W,
                                            unsigned short* __restrict__ WTb) {
    const int ncol = blockIdx.x;
    const int k = threadIdx.x;
    WTb[(size_t)ncol * 256 + k] = f2bf(W[(size_t)k * 128 + ncol]);
}

// ---- fused GEMM: stages fp32 x -> bf16 LDS, MFMA, writes hb + f_src/f_dst ----
__global__ __launch_bounds__(256) void k_gemm(const float* __restrict__ x,
                                              const unsigned short* __restrict__ WTb,
                                              const float* __restrict__ a,
                                              unsigned short* __restrict__ hb,
                                              float* __restrict__ f_src,
                                              float* __restrict__ f_dst, int n) {
    __shared__ unsigned short sA[128 * LDA];   // 67.6 KB, padded stride
    __shared__ float sFp[128][2][2];           // [row][wc][src/dst]
    const int t = threadIdx.x;
    const int l = t & 63;
    const int w = t >> 6;
    const int wr = w >> 1, wc = w & 1;
    const int row0 = blockIdx.x * 128;
    const int col0 = wc * 64;
    const int lr = l & 15;
    const int g = l >> 4;
    const int lk8 = g * 8;

    // ---- stage x tile: fp32 coalesced -> bf16 LDS (convert once) ----
    {
        const int rr = t >> 5;          // 0..7
        const int cc = (t & 31) * 8;    // 0..248
        #pragma unroll
        for (int it = 0; it < 16; ++it) {
            int r = it * 8 + rr;
            int gr = row0 + r;
            float4 fa, fb;
            if (gr < n) {
                fa = *(const float4*)&x[(size_t)gr * D_IN + cc];
                fb = *(const float4*)&x[(size_t)gr * D_IN + cc + 4];
            } else {
                fa = make_float4(0.f, 0.f, 0.f, 0.f);
                fb = fa;
            }
            bf16x8 v;
            v[0] = (short)f2bf(fa.x); v[1] = (short)f2bf(fa.y);
            v[2] = (short)f2bf(fa.z); v[3] = (short)f2bf(fa.w);
            v[4] = (short)f2bf(fb.x); v[5] = (short)f2bf(fb.y);
            v[6] = (short)f2bf(fb.z); v[7] = (short)f2bf(fb.w);
            *(bf16x8*)&sA[r * LDA + cc] = v;
        }
    }
    __syncthreads();

    f32x4 acc[4][4] = {};
    const unsigned short* bp[4];
    #pragma unroll
    for (int ni = 0; ni < 4; ++ni)
        bp[ni] = WTb + (size_t)(col0 + ni * 16 + lr) * 256 + lk8;

    #pragma unroll
    for (int k0 = 0; k0 < D_IN; k0 += 32) {
        bf16x8 af[4], bfr[4];
        #pragma unroll
        for (int mi = 0; mi < 4; ++mi)
            af[mi] = *(const bf16x8*)&sA[(wr * 64 + mi * 16 + lr) * LDA + k0 + lk8];
        #pragma unroll
        for (int ni = 0; ni < 4; ++ni) bfr[ni] = *(const bf16x8*)(bp[ni] + k0);
        #pragma unroll
        for (int mi = 0; mi < 4; ++mi)
            #pragma unroll
            for (int ni = 0; ni < 4; ++ni)
                acc[mi][ni] = __builtin_amdgcn_mfma_f32_16x16x32_bf16(
                    af[mi], bfr[ni], acc[mi][ni], 0, 0, 0);
    }

    // ---- hb store (C/D: col = lane&15, row = g*4 + q) ----
    const int rq = g * 4;
    #pragma unroll
    for (int mi = 0; mi < 4; ++mi) {
        #pragma unroll
        for (int q = 0; q < 4; ++q) {
            int r = row0 + wr * 64 + mi * 16 + rq + q;
            if (r < n) {
                #pragma unroll
                for (int ni = 0; ni < 4; ++ni)
                    hb[(size_t)r * D_OUT + col0 + ni * 16 + lr] =
                        f2bf(acc[mi][ni][q]);
            }
        }
    }

    // ---- fused f_src/f_dst from fp32 acc ----
    float asv[4], adv[4];
    #pragma unroll
    for (int ni = 0; ni < 4; ++ni) {
        asv[ni] = a[col0 + ni * 16 + lr];
        adv[ni] = a[D_OUT + col0 + ni * 16 + lr];
    }
    #pragma unroll
    for (int mi = 0; mi < 4; ++mi) {
        #pragma unroll
        for (int q = 0; q < 4; ++q) {
            float fs = 0.f, fd = 0.f;
            #pragma unroll
            for (int ni = 0; ni < 4; ++ni) {
                float v = acc[mi][ni][q];
                fs = fmaf(v, asv[ni], fs);
                fd = fmaf(v, adv[ni], fd);
            }
            #pragma unroll
            for (int m = 1; m < 16; m <<= 1) {
                fs += __shfl_xor(fs, m);
                fd += __shfl_xor(fd, m);
            }
            if (lr == 0) {
                int rl = wr * 64 + mi * 16 + g * 4 + q;
                sFp[rl][wc][0] = fs;
                sFp[rl][wc][1] = fd;
            }
        }
    }
    __syncthreads();
    if (t < 128) {
        int r = row0 + t;
        if (r < n) {
            f_src[r] = sFp[t][0][0] + sFp[t][1][0];
            f_dst[r] = sFp[t][0][1] + sFp[t][1][1];
        }
    }
}

// ---------------- bucket histogram (LDS-privatized, int atomics) ----------------
__global__ __launch_bounds__(256) void k_bhist(const int* __restrict__ src,
                                               int* __restrict__ ghist, int E, int nb) {
    __shared__ int lh[NBMAX];
    for (int i = threadIdx.x; i < nb; i += 256) lh[i] = 0;
    __syncthreads();
    for (int e = blockIdx.x * 256 + threadIdx.x; e < E; e += gridDim.x * 256)
        atomicAdd(&lh[src[e] >> RBSH], 1);
    __syncthreads();
    for (int i = threadIdx.x; i < nb; i += 256) {
        int c = lh[i];
        if (c) atomicAdd(&ghist[i], c);
    }
}

// ---------------- bucket scan (nb <= 2048) ----------------
__global__ __launch_bounds__(256) void k_bscan(const int* __restrict__ ghist,
                                               int* __restrict__ gbase,
                                               int* __restrict__ gcur, int nb, int E) {
    const int t = threadIdx.x;
    const int i0 = t * 8;
    int v[8];
    int tot = 0;
    #pragma unroll
    for (int j = 0; j < 8; ++j) {
        int i = i0 + j;
        v[j] = (i < nb) ? ghist[i] : 0;
        tot += v[j];
    }
    __shared__ int sc[256];
    sc[t] = tot;
    __syncthreads();
    #pragma unroll
    for (int off = 1; off < 256; off <<= 1) {
        int add = (t >= off) ? sc[t - off] : 0;
        __syncthreads();
        sc[t] += add;
        __syncthreads();
    }
    int base = sc[t] - tot;
    int run = 0;
    #pragma unroll
    for (int j = 0; j < 8; ++j) {
        int i = i0 + j;
        if (i < nb) {
            gbase[i] = base + run;
            gcur[i]  = base + run;
        }
        run += v[j];
    }
    if (t == 255) gbase[nb] = E;
}

// ---------------- bucket fill: packed keys (lsrc<<17 | dst) ----------------
__global__ __launch_bounds__(256) void k_bfill(const int* __restrict__ src,
                                               const int* __restrict__ dst,
                                               int* __restrict__ gcur,
                                               int* __restrict__ gkeys, int E, int nb) {
    __shared__ int cnt[NBMAX];
    __shared__ int bas[NBMAX];
    const int t = threadIdx.x;
    const int e0 = blockIdx.x * CH;
    const int e1 = min(e0 + CH, E);
    for (int i = t; i < nb; i += 256) cnt[i] = 0;
    __syncthreads();
    for (int e = e0 + t; e < e1; e += 256) atomicAdd(&cnt[src[e] >> RBSH], 1);
    __syncthreads();
    for (int b = t; b < nb; b += 256) {
        int c = cnt[b];
        bas[b] = c ? atomicAdd(&gcur[b], c) : 0;
        cnt[b] = 0;
    }
    __syncthreads();
    for (int e = e0 + t; e < e1; e += 256) {
        int s = src[e], d = dst[e];
        int b = s >> RBSH;
        int r = atomicAdd(&cnt[b], 1);
        gkeys[bas[b] + r] = ((s & (RB - 1)) << 17) | d;
    }
}

// -------- aggregation: block/bucket, 512 threads, LDS lists, reg accum --------
__global__ __launch_bounds__(512) void k_bagg(const unsigned short* __restrict__ hb,
                                              const float* __restrict__ f_src,
                                              const float* __restrict__ f_dst,
                                              const int* __restrict__ gbase,
                                              const int* __restrict__ gkeys,
                                              float* __restrict__ out, int n) {
    __shared__ int2 sdw[CAP];        // (dst, weight-bits), grouped by local src
    __shared__ int nbase[RB];
    __shared__ int ncnt[RB];
    __shared__ int ncur[RB];
    __shared__ float fsl[RB];
    __shared__ int sc[RB];
    const int t = threadIdx.x;
    const int b = blockIdx.x;
    const int s0 = b * RB;
    const int nn = min(RB, n - s0);
    const int beg = gbase[b], end = gbase[b + 1];
    const int m = min(end - beg, CAP);

    for (int i = t; i < RB; i += 512) {
        ncnt[i] = 0;
        fsl[i] = (i < nn) ? f_src[s0 + i] : 0.f;
    }
    __syncthreads();

    // pass 1: per-node histogram (native int LDS atomics)
    for (int i = t; i < m; i += 512)
        atomicAdd(&ncnt[gkeys[beg + i] >> 17], 1);
    __syncthreads();

    // scan of RB counters
    if (t < RB) sc[t] = ncnt[t];
    __syncthreads();
    for (int off = 1; off < RB; off <<= 1) {
        int v = 0;
        if (t < RB && t >= off) v = sc[t - off];
        __syncthreads();
        if (t < RB) sc[t] += v;
        __syncthreads();
    }
    if (t < RB) {
        nbase[t] = sc[t] - ncnt[t];
        ncur[t]  = sc[t] - ncnt[t];
    }
    __syncthreads();

    // pass 2: scatter (d, w) grouped by local src; weights lane-parallel
    for (int i = t; i < m; i += 512) {
        int k = gkeys[beg + i];
        int d = k & 0x1FFFF, ls = k >> 17;
        float tmp = fsl[ls] + f_dst[d];
        float w = __expf(-((tmp > 0.f) ? tmp : ALPHA * tmp));
        int pos = atomicAdd(&ncur[ls], 1);
        sdw[pos] = make_int2(d, __float_as_int(w));
    }
    __syncthreads();

    // pass 3: wave-per-node register accumulation
    const int lane = t & 63, wid = t >> 6;
    for (int ni = wid; ni < nn; ni += 8) {
        const int jb = nbase[ni];
        const int je = jb + ncnt[ni];
        float acc0 = 0.f, acc1 = 0.f, rowsum = 0.f;
        #pragma unroll 8
        for (int j = jb; j < je; ++j) {
            int2 dw = sdw[j];                    // uniform address -> broadcast
            float w = __int_as_float(dw.y);
            ushort2 hv = *(const ushort2*)&hb[(size_t)dw.x * D_OUT + lane * 2];
            rowsum += w;
            acc0 = fmaf(w, bf2f(hv.x), acc0);
            acc1 = fmaf(w, bf2f(hv.y), acc1);
        }
        // overflow fallback (never triggers for this input; zero cost when m == end-beg)
        for (int j = beg + m; j < end; ++j) {
            int k = gkeys[j];
            if ((k >> 17) == ni) {
                int d = k & 0x1FFFF;
                float tmp = fsl[ni] + f_dst[d];
                float w = __expf(-((tmp > 0.f) ? tmp : ALPHA * tmp));
                ushort2 hv = *(const ushort2*)&hb[(size_t)d * D_OUT + lane * 2];
                rowsum += w;
                acc0 = fmaf(w, bf2f(hv.x), acc0);
                acc1 = fmaf(w, bf2f(hv.y), acc1);
            }
        }
        float inv = 1.f / rowsum;
        acc0 *= inv;
        acc1 *= inv;
        acc0 = (acc0 > 0.f) ? acc0 : (__expf(acc0) - 1.f);
        acc1 = (acc1 > 0.f) ? acc1 : (__expf(acc1) - 1.f);
        *(float2*)&out[(size_t)(s0 + ni) * D_OUT + lane * 2] = make_float2(acc0, acc1);
    }
}

extern "C" void kernel_launch(void* const* d_in, const int* in_sizes, int n_in,
                              void* d_out, int out_size, void* d_ws, size_t ws_size,
                              hipStream_t stream) {
    const float* x    = (const float*)d_in[0];
    const int*   edge = (const int*)d_in[1];   // JAX no-x64: int64 -> int32
    const float* W    = (const float*)d_in[2];
    const float* a    = (const float*)d_in[3];
    float* out = (float*)d_out;

    const int n = in_sizes[0] / D_IN;
    const int E = in_sizes[1] / 2;
    const int* src = edge;
    const int* dst = edge + E;
    const int nb = (n + RB - 1) / RB;

    char* p = (char*)d_ws;
    unsigned short* hb  = (unsigned short*)p; p += (size_t)n * D_OUT * sizeof(unsigned short);
    unsigned short* WTb = (unsigned short*)p; p += (size_t)D_OUT * D_IN * sizeof(unsigned short);
    float* f_src = (float*)p;  p += (size_t)n * sizeof(float);
    float* f_dst = (float*)p;  p += (size_t)n * sizeof(float);
    int* ghist   = (int*)p;    p += (size_t)nb * sizeof(int);
    int* gbase   = (int*)p;    p += (size_t)(nb + 1) * sizeof(int);
    int* gcur    = (int*)p;    p += (size_t)nb * sizeof(int);
    int* gkeys   = (int*)p;    p += (size_t)E * sizeof(int);

    const int gemm_blocks = (n + 127) / 128;

    k_wt<<<D_OUT, 256, 0, stream>>>(W, WTb);
    k_gemm<<<gemm_blocks, 256, 0, stream>>>(x, WTb, a, hb, f_src, f_dst, n);

    hipMemsetAsync(ghist, 0, (size_t)nb * sizeof(int), stream);
    k_bhist<<<128, 256, 0, stream>>>(src, ghist, E, nb);
    k_bscan<<<1, 256, 0, stream>>>(ghist, gbase, gcur, nb, E);
    k_bfill<<<(E + CH - 1) / CH, 256, 0, stream>>>(src, dst, gcur, gkeys, E, nb);
    k_bagg<<<nb, 512, 0, stream>>>(hb, f_src, f_dst, gbase, gkeys, out, n);
}

// Round 8
// 158.017 us; speedup vs baseline: 9.3249x; 1.1210x over previous
//
#include <hip/hip_runtime.h>

#define D_IN 256
#define D_OUT 128
#define ALPHA 0.2f
#define RB 64           // src nodes per bucket
#define RBSH 6
#define NBMAX 1600
#define CH 8192         // edges per k_bfill block
#define CAPG 1536       // fixed per-bucket key capacity (mean 1024, +16 sigma)
#define OVFCAP 32768
#define LDA 264         // padded LDS row stride in ushorts (528 B)

typedef __attribute__((ext_vector_type(8))) short bf16x8;
typedef __attribute__((ext_vector_type(4))) float f32x4;

__device__ inline unsigned short f2bf(float f) {
    unsigned int u = __float_as_uint(f);
    return (unsigned short)((u + 0x7FFFu + ((u >> 16) & 1u)) >> 16);
}
__device__ inline float bf2f(unsigned short u) {
    return __uint_as_float(((unsigned int)u) << 16);
}

// ---------------- W -> WTb (transposed bf16) ----------------
__global__ __launch_bounds__(256) void k_wt(const float* __restrict__ W,
                                            unsigned short* __restrict__ WTb) {
    const int ncol = blockIdx.x;
    const int k = threadIdx.x;
    WTb[(size_t)ncol * 256 + k] = f2bf(W[(size_t)k * 128 + ncol]);
}

// ---- fused GEMM (BM=64): stage fp32 x->bf16 LDS, MFMA, hb + f_src/f_dst ----
__global__ __launch_bounds__(256, 4) void k_gemm(const float* __restrict__ x,
                                                 const unsigned short* __restrict__ WTb,
                                                 const float* __restrict__ a,
                                                 unsigned short* __restrict__ hb,
                                                 float* __restrict__ f_src,
                                                 float* __restrict__ f_dst, int n) {
    __shared__ unsigned short sA[64 * LDA];    // 33.8 KB
    __shared__ float sFp[64][2][2];            // [row][wc][src/dst]
    const int t = threadIdx.x;
    const int l = t & 63;
    const int w = t >> 6;
    const int wr = w >> 1, wc = w & 1;
    const int row0 = blockIdx.x * 64;
    const int col0 = wc * 64;
    const int lr = l & 15;
    const int g = l >> 4;
    const int lk8 = g * 8;

    // ---- stage x tile: fp32 coalesced -> bf16 LDS ----
    {
        const int rr = t >> 5;          // 0..7
        const int cc = (t & 31) * 8;    // 0..248
        #pragma unroll
        for (int it = 0; it < 8; ++it) {
            int r = it * 8 + rr;
            int gr = row0 + r;
            float4 fa, fb;
            if (gr < n) {
                fa = *(const float4*)&x[(size_t)gr * D_IN + cc];
                fb = *(const float4*)&x[(size_t)gr * D_IN + cc + 4];
            } else {
                fa = make_float4(0.f, 0.f, 0.f, 0.f);
                fb = fa;
            }
            bf16x8 v;
            v[0] = (short)f2bf(fa.x); v[1] = (short)f2bf(fa.y);
            v[2] = (short)f2bf(fa.z); v[3] = (short)f2bf(fa.w);
            v[4] = (short)f2bf(fb.x); v[5] = (short)f2bf(fb.y);
            v[6] = (short)f2bf(fb.z); v[7] = (short)f2bf(fb.w);
            *(bf16x8*)&sA[r * LDA + cc] = v;
        }
    }
    __syncthreads();

    f32x4 acc[2][4] = {};
    const unsigned short* bp[4];
    #pragma unroll
    for (int ni = 0; ni < 4; ++ni)
        bp[ni] = WTb + (size_t)(col0 + ni * 16 + lr) * 256 + lk8;

    #pragma unroll
    for (int k0 = 0; k0 < D_IN; k0 += 32) {
        bf16x8 af[2], bfr[4];
        #pragma unroll
        for (int mi = 0; mi < 2; ++mi)
            af[mi] = *(const bf16x8*)&sA[(wr * 32 + mi * 16 + lr) * LDA + k0 + lk8];
        #pragma unroll
        for (int ni = 0; ni < 4; ++ni) bfr[ni] = *(const bf16x8*)(bp[ni] + k0);
        #pragma unroll
        for (int mi = 0; mi < 2; ++mi)
            #pragma unroll
            for (int ni = 0; ni < 4; ++ni)
                acc[mi][ni] = __builtin_amdgcn_mfma_f32_16x16x32_bf16(
                    af[mi], bfr[ni], acc[mi][ni], 0, 0, 0);
    }

    // ---- hb store (C/D: col = lane&15, row = g*4 + q) ----
    #pragma unroll
    for (int mi = 0; mi < 2; ++mi) {
        #pragma unroll
        for (int q = 0; q < 4; ++q) {
            int r = row0 + wr * 32 + mi * 16 + g * 4 + q;
            if (r < n) {
                #pragma unroll
                for (int ni = 0; ni < 4; ++ni)
                    hb[(size_t)r * D_OUT + col0 + ni * 16 + lr] =
                        f2bf(acc[mi][ni][q]);
            }
        }
    }

    // ---- fused f_src/f_dst from fp32 acc ----
    float asv[4], adv[4];
    #pragma unroll
    for (int ni = 0; ni < 4; ++ni) {
        asv[ni] = a[col0 + ni * 16 + lr];
        adv[ni] = a[D_OUT + col0 + ni * 16 + lr];
    }
    #pragma unroll
    for (int mi = 0; mi < 2; ++mi) {
        #pragma unroll
        for (int q = 0; q < 4; ++q) {
            float fs = 0.f, fd = 0.f;
            #pragma unroll
            for (int ni = 0; ni < 4; ++ni) {
                float v = acc[mi][ni][q];
                fs = fmaf(v, asv[ni], fs);
                fd = fmaf(v, adv[ni], fd);
            }
            #pragma unroll
            for (int m = 1; m < 16; m <<= 1) {
                fs += __shfl_xor(fs, m);
                fd += __shfl_xor(fd, m);
            }
            if (lr == 0) {
                int rl = wr * 32 + mi * 16 + g * 4 + q;
                sFp[rl][wc][0] = fs;
                sFp[rl][wc][1] = fd;
            }
        }
    }
    __syncthreads();
    if (t < 64) {
        int r = row0 + t;
        if (r < n) {
            f_src[r] = sFp[t][0][0] + sFp[t][1][0];
            f_dst[r] = sFp[t][0][1] + sFp[t][1][1];
        }
    }
}

// ---- bucket fill: fixed-capacity slabs, packed keys (lsrc<<17 | dst) ----
__global__ __launch_bounds__(256) void k_bfill(const int* __restrict__ src,
                                               const int* __restrict__ dst,
                                               int* __restrict__ gcnt,   // [nb+1], last = ovf_cnt
                                               int2* __restrict__ ovf,
                                               int* __restrict__ gkeys, int E, int nb) {
    __shared__ int cnt[NBMAX];
    __shared__ int bas[NBMAX];
    const int t = threadIdx.x;
    const int e0 = blockIdx.x * CH;
    const int e1 = min(e0 + CH, E);
    for (int i = t; i < nb; i += 256) cnt[i] = 0;
    __syncthreads();
    for (int e = e0 + t; e < e1; e += 256) atomicAdd(&cnt[src[e] >> RBSH], 1);
    __syncthreads();
    for (int b = t; b < nb; b += 256) {
        int c = cnt[b];
        bas[b] = c ? atomicAdd(&gcnt[b], c) : 0;
        cnt[b] = 0;
    }
    __syncthreads();
    for (int e = e0 + t; e < e1; e += 256) {
        int s = src[e], d = dst[e];
        int b = s >> RBSH;
        int key = ((s & (RB - 1)) << 17) | d;
        int r = bas[b] + atomicAdd(&cnt[b], 1);
        if (r < CAPG) {
            gkeys[b * CAPG + r] = key;
        } else {
            int o = atomicAdd(&gcnt[nb], 1);
            if (o < OVFCAP) ovf[o] = make_int2(b, key);
        }
    }
}

// -------- aggregation: block/bucket, LDS lists, 2-edge 32-lane pass 3 --------
__global__ __launch_bounds__(512, 8) void k_bagg(const unsigned short* __restrict__ hb,
                                                 const float* __restrict__ f_src,
                                                 const float* __restrict__ f_dst,
                                                 const int* __restrict__ gcnt,
                                                 const int2* __restrict__ ovf,
                                                 const int* __restrict__ gkeys,
                                                 float* __restrict__ out, int n, int nb) {
    __shared__ int2 sdw[CAPG];       // (dst, weight-bits), grouped by local src
    __shared__ int nbase[RB];
    __shared__ int ncnt[RB];
    __shared__ int ncur[RB];
    __shared__ float fsl[RB];
    __shared__ int sc[RB];
    const int t = threadIdx.x;
    const int b = blockIdx.x;
    const int s0 = b * RB;
    const int nn = min(RB, n - s0);
    const int beg = b * CAPG;
    const int stored = min(gcnt[b], CAPG);
    const int ovf_n = min(gcnt[nb], OVFCAP);

    for (int i = t; i < RB; i += 512) {
        ncnt[i] = 0;
        fsl[i] = (i < nn) ? f_src[s0 + i] : 0.f;
    }
    __syncthreads();

    // pass 1: per-node histogram (native int LDS atomics)
    for (int i = t; i < stored; i += 512)
        atomicAdd(&ncnt[gkeys[beg + i] >> 17], 1);
    __syncthreads();

    // scan of RB counters
    if (t < RB) sc[t] = ncnt[t];
    __syncthreads();
    for (int off = 1; off < RB; off <<= 1) {
        int v = 0;
        if (t < RB && t >= off) v = sc[t - off];
        __syncthreads();
        if (t < RB) sc[t] += v;
        __syncthreads();
    }
    if (t < RB) {
        nbase[t] = sc[t] - ncnt[t];
        ncur[t]  = sc[t] - ncnt[t];
    }
    __syncthreads();

    // pass 2: scatter (d, w) grouped by local src; weights lane-parallel
    for (int i = t; i < stored; i += 512) {
        int k = gkeys[beg + i];
        int d = k & 0x1FFFF, ls = k >> 17;
        float tmp = fsl[ls] + f_dst[d];
        float w = __expf(-((tmp > 0.f) ? tmp : ALPHA * tmp));
        int pos = atomicAdd(&ncur[ls], 1);
        sdw[pos] = make_int2(d, __float_as_int(w));
    }
    __syncthreads();

    // pass 3: wave-per-node, two edges per iteration (32-lane halves)
    const int lane = t & 63, wid = t >> 6;
    const int cl = (lane & 31) * 4;          // 4 cols per lane within half
    const bool isB = lane >= 32;
    for (int ni = wid; ni < nn; ni += 8) {
        const int jb = nbase[ni];
        const int cn = ncnt[ni];
        const int halfA = (cn + 1) >> 1;
        const int halfB = cn - halfA;
        const int lim = isB ? halfB : halfA;
        const int jbh = jb + (isB ? halfA : 0);
        float a0 = 0.f, a1 = 0.f, a2 = 0.f, a3 = 0.f, rowsum = 0.f;
        #pragma unroll 4
        for (int it = 0; it < halfA; ++it) {
            bool valid = it < lim;
            int2 dw = sdw[valid ? (jbh + it) : jb];
            float w = valid ? __int_as_float(dw.y) : 0.f;
            ushort4 hv = *(const ushort4*)&hb[(size_t)dw.x * D_OUT + cl];
            rowsum += w;
            a0 = fmaf(w, bf2f(hv.x), a0);
            a1 = fmaf(w, bf2f(hv.y), a1);
            a2 = fmaf(w, bf2f(hv.z), a2);
            a3 = fmaf(w, bf2f(hv.w), a3);
        }
        // overflow fallback (only when bucket exceeded CAPG; ~never)
        if (ovf_n > 0) {
            for (int o = 0; o < ovf_n; ++o) {
                int2 ov = ovf[o];
                if (ov.x == b && (ov.y >> 17) == ni && !isB) {
                    int d = ov.y & 0x1FFFF;
                    float tmp = fsl[ni] + f_dst[d];
                    float w = __expf(-((tmp > 0.f) ? tmp : ALPHA * tmp));
                    ushort4 hv = *(const ushort4*)&hb[(size_t)d * D_OUT + cl];
                    rowsum += w;
                    a0 = fmaf(w, bf2f(hv.x), a0);
                    a1 = fmaf(w, bf2f(hv.y), a1);
                    a2 = fmaf(w, bf2f(hv.z), a2);
                    a3 = fmaf(w, bf2f(hv.w), a3);
                }
            }
        }
        // combine halves
        rowsum += __shfl_xor(rowsum, 32);
        a0 += __shfl_xor(a0, 32);
        a1 += __shfl_xor(a1, 32);
        a2 += __shfl_xor(a2, 32);
        a3 += __shfl_xor(a3, 32);
        if (!isB) {
            float inv = 1.f / rowsum;
            a0 *= inv; a1 *= inv; a2 *= inv; a3 *= inv;
            a0 = (a0 > 0.f) ? a0 : (__expf(a0) - 1.f);
            a1 = (a1 > 0.f) ? a1 : (__expf(a1) - 1.f);
            a2 = (a2 > 0.f) ? a2 : (__expf(a2) - 1.f);
            a3 = (a3 > 0.f) ? a3 : (__expf(a3) - 1.f);
            *(float4*)&out[(size_t)(s0 + ni) * D_OUT + cl] =
                make_float4(a0, a1, a2, a3);
        }
    }
}

extern "C" void kernel_launch(void* const* d_in, const int* in_sizes, int n_in,
                              void* d_out, int out_size, void* d_ws, size_t ws_size,
                              hipStream_t stream) {
    const float* x    = (const float*)d_in[0];
    const int*   edge = (const int*)d_in[1];   // JAX no-x64: int64 -> int32
    const float* W    = (const float*)d_in[2];
    const float* a    = (const float*)d_in[3];
    float* out = (float*)d_out;

    const int n = in_sizes[0] / D_IN;
    const int E = in_sizes[1] / 2;
    const int* src = edge;
    const int* dst = edge + E;
    const int nb = (n + RB - 1) / RB;

    char* p = (char*)d_ws;
    unsigned short* hb  = (unsigned short*)p; p += (size_t)n * D_OUT * sizeof(unsigned short);
    unsigned short* WTb = (unsigned short*)p; p += (size_t)D_OUT * D_IN * sizeof(unsigned short);
    float* f_src = (float*)p;  p += (size_t)n * sizeof(float);
    float* f_dst = (float*)p;  p += (size_t)n * sizeof(float);
    int*  gcnt   = (int*)p;    p += (size_t)(nb + 1) * sizeof(int);
    int2* ovf    = (int2*)p;   p += (size_t)OVFCAP * sizeof(int2);
    int*  gkeys  = (int*)p;    p += (size_t)nb * CAPG * sizeof(int);

    const int gemm_blocks = (n + 63) / 64;

    k_wt<<<D_OUT, 256, 0, stream>>>(W, WTb);
    k_gemm<<<gemm_blocks, 256, 0, stream>>>(x, WTb, a, hb, f_src, f_dst, n);

    hipMemsetAsync(gcnt, 0, (size_t)(nb + 1) * sizeof(int), stream);
    k_bfill<<<(E + CH - 1) / CH, 256, 0, stream>>>(src, dst, gcnt, ovf, gkeys, E, nb);
    k_bagg<<<nb, 512, 0, stream>>>(hb, f_src, f_dst, gcnt, ovf, gkeys, out, n, nb);
}

// Round 9
// 152.159 us; speedup vs baseline: 9.6839x; 1.0385x over previous
//
#include <hip/hip_runtime.h>

#define D_IN 256
#define D_OUT 128
#define ALPHA 0.2f
#define RB 64           // src nodes per bucket
#define RBSH 6
#define NBMAX 1600
#define CH 8192         // edges per k_bfill block
#define CAPG 1536       // fixed per-bucket key capacity (mean 1024, +16 sigma)
#define OVFCAP 32768
#define LKH 128         // K-half staged in LDS (ushorts per row)

typedef __attribute__((ext_vector_type(8))) short bf16x8;
typedef __attribute__((ext_vector_type(4))) float f32x4;

__device__ inline unsigned short f2bf(float f) {
    unsigned int u = __float_as_uint(f);
    return (unsigned short)((u + 0x7FFFu + ((u >> 16) & 1u)) >> 16);
}
__device__ inline float bf2f(unsigned short u) {
    return __uint_as_float(((unsigned int)u) << 16);
}

// ---------------- W -> WTb (transposed bf16) ----------------
__global__ __launch_bounds__(256) void k_wt(const float* __restrict__ W,
                                            unsigned short* __restrict__ WTb) {
    const int ncol = blockIdx.x;
    const int k = threadIdx.x;
    WTb[(size_t)ncol * 256 + k] = f2bf(W[(size_t)k * 128 + ncol]);
}

// ---- fused GEMM (BM=128, K staged in 2 halves, XOR-swizzled LDS) ----
__global__ __launch_bounds__(256) void k_gemm(const float* __restrict__ x,
                                              const unsigned short* __restrict__ WTb,
                                              const float* __restrict__ a,
                                              unsigned short* __restrict__ hb,
                                              float* __restrict__ f_src,
                                              float* __restrict__ f_dst, int n) {
    __shared__ unsigned short sA[128 * LKH];   // 32 KB, swizzled 16B blocks
    __shared__ float sFp[128][2][2];           // [row][wc][src/dst], 2 KB
    const int t = threadIdx.x;
    const int l = t & 63;
    const int w = t >> 6;
    const int wr = w >> 1, wc = w & 1;
    const int row0 = blockIdx.x * 128;
    const int col0 = wc * 64;
    const int lr = l & 15;
    const int g = l >> 4;
    const int lk8 = g * 8;

    f32x4 acc[4][4] = {};
    const unsigned short* bp[4];
    #pragma unroll
    for (int ni = 0; ni < 4; ++ni)
        bp[ni] = WTb + (size_t)(col0 + ni * 16 + lr) * 256 + lk8;

    #pragma unroll
    for (int half = 0; half < 2; ++half) {
        // ---- stage x[:, half*128 .. half*128+127] fp32 -> bf16 LDS ----
        {
            const int rr = t >> 4;          // 0..15
            const int cc = (t & 15) * 8;    // 0..120
            #pragma unroll
            for (int it = 0; it < 8; ++it) {
                int r = it * 16 + rr;
                int gr = row0 + r;
                float4 fa, fb;
                if (gr < n) {
                    const float* xp = &x[(size_t)gr * D_IN + half * LKH + cc];
                    fa = *(const float4*)xp;
                    fb = *(const float4*)(xp + 4);
                } else {
                    fa = make_float4(0.f, 0.f, 0.f, 0.f);
                    fb = fa;
                }
                bf16x8 v;
                v[0] = (short)f2bf(fa.x); v[1] = (short)f2bf(fa.y);
                v[2] = (short)f2bf(fa.z); v[3] = (short)f2bf(fa.w);
                v[4] = (short)f2bf(fb.x); v[5] = (short)f2bf(fb.y);
                v[6] = (short)f2bf(fb.z); v[7] = (short)f2bf(fb.w);
                int js = (cc >> 3) ^ ((r & 7) << 1);   // swizzled 16B block
                *(bf16x8*)&sA[r * LKH + js * 8] = v;
            }
        }
        __syncthreads();

        #pragma unroll
        for (int k0 = 0; k0 < LKH; k0 += 32) {
            bf16x8 af[4], bfr[4];
            #pragma unroll
            for (int mi = 0; mi < 4; ++mi) {
                int row_l = wr * 64 + mi * 16 + lr;
                int js = ((k0 >> 3) + g) ^ ((row_l & 7) << 1);
                af[mi] = *(const bf16x8*)&sA[row_l * LKH + js * 8];
            }
            #pragma unroll
            for (int ni = 0; ni < 4; ++ni)
                bfr[ni] = *(const bf16x8*)(bp[ni] + half * LKH + k0);
            #pragma unroll
            for (int mi = 0; mi < 4; ++mi)
                #pragma unroll
                for (int ni = 0; ni < 4; ++ni)
                    acc[mi][ni] = __builtin_amdgcn_mfma_f32_16x16x32_bf16(
                        af[mi], bfr[ni], acc[mi][ni], 0, 0, 0);
        }
        __syncthreads();
    }

    // ---- hb store (C/D: col = lane&15, row = g*4 + q) ----
    #pragma unroll
    for (int mi = 0; mi < 4; ++mi) {
        #pragma unroll
        for (int q = 0; q < 4; ++q) {
            int r = row0 + wr * 64 + mi * 16 + g * 4 + q;
            if (r < n) {
                #pragma unroll
                for (int ni = 0; ni < 4; ++ni)
                    hb[(size_t)r * D_OUT + col0 + ni * 16 + lr] =
                        f2bf(acc[mi][ni][q]);
            }
        }
    }

    // ---- fused f_src/f_dst from fp32 acc ----
    float asv[4], adv[4];
    #pragma unroll
    for (int ni = 0; ni < 4; ++ni) {
        asv[ni] = a[col0 + ni * 16 + lr];
        adv[ni] = a[D_OUT + col0 + ni * 16 + lr];
    }
    #pragma unroll
    for (int mi = 0; mi < 4; ++mi) {
        #pragma unroll
        for (int q = 0; q < 4; ++q) {
            float fs = 0.f, fd = 0.f;
            #pragma unroll
            for (int ni = 0; ni < 4; ++ni) {
                float v = acc[mi][ni][q];
                fs = fmaf(v, asv[ni], fs);
                fd = fmaf(v, adv[ni], fd);
            }
            #pragma unroll
            for (int m = 1; m < 16; m <<= 1) {
                fs += __shfl_xor(fs, m);
                fd += __shfl_xor(fd, m);
            }
            if (lr == 0) {
                int rl = wr * 64 + mi * 16 + g * 4 + q;
                sFp[rl][wc][0] = fs;
                sFp[rl][wc][1] = fd;
            }
        }
    }
    __syncthreads();
    if (t < 128) {
        int r = row0 + t;
        if (r < n) {
            f_src[r] = sFp[t][0][0] + sFp[t][1][0];
            f_dst[r] = sFp[t][0][1] + sFp[t][1][1];
        }
    }
}

// ---- bucket fill: fixed-capacity slabs, packed keys (lsrc<<17 | dst) ----
__global__ __launch_bounds__(256) void k_bfill(const int* __restrict__ src,
                                               const int* __restrict__ dst,
                                               int* __restrict__ gcnt,   // [nb+1], last = ovf_cnt
                                               int2* __restrict__ ovf,
                                               int* __restrict__ gkeys, int E, int nb) {
    __shared__ int cnt[NBMAX];
    __shared__ int bas[NBMAX];
    const int t = threadIdx.x;
    const int e0 = blockIdx.x * CH;
    const int e1 = min(e0 + CH, E);
    for (int i = t; i < nb; i += 256) cnt[i] = 0;
    __syncthreads();
    for (int e = e0 + t; e < e1; e += 256) atomicAdd(&cnt[src[e] >> RBSH], 1);
    __syncthreads();
    for (int b = t; b < nb; b += 256) {
        int c = cnt[b];
        bas[b] = c ? atomicAdd(&gcnt[b], c) : 0;
        cnt[b] = 0;
    }
    __syncthreads();
    for (int e = e0 + t; e < e1; e += 256) {
        int s = src[e], d = dst[e];
        int b = s >> RBSH;
        int key = ((s & (RB - 1)) << 17) | d;
        int r = bas[b] + atomicAdd(&cnt[b], 1);
        if (r < CAPG) {
            gkeys[b * CAPG + r] = key;
        } else {
            int o = atomicAdd(&gcnt[nb], 1);
            if (o < OVFCAP) ovf[o] = make_int2(b, key);
        }
    }
}

// -------- aggregation: block/bucket, LDS lists, 2-edge 32-lane pass 3 --------
__global__ __launch_bounds__(512, 8) void k_bagg(const unsigned short* __restrict__ hb,
                                                 const float* __restrict__ f_src,
                                                 const float* __restrict__ f_dst,
                                                 const int* __restrict__ gcnt,
                                                 const int2* __restrict__ ovf,
                                                 const int* __restrict__ gkeys,
                                                 float* __restrict__ out, int n, int nb) {
    __shared__ int2 sdw[CAPG];       // (dst, weight-bits), grouped by local src
    __shared__ int nbase[RB];
    __shared__ int ncnt[RB];
    __shared__ int ncur[RB];
    __shared__ float fsl[RB];
    __shared__ int sc[RB];
    const int t = threadIdx.x;
    const int b = blockIdx.x;
    const int s0 = b * RB;
    const int nn = min(RB, n - s0);
    const int beg = b * CAPG;
    const int stored = min(gcnt[b], CAPG);
    const int ovf_n = min(gcnt[nb], OVFCAP);

    for (int i = t; i < RB; i += 512) {
        ncnt[i] = 0;
        fsl[i] = (i < nn) ? f_src[s0 + i] : 0.f;
    }
    __syncthreads();

    // pass 1: per-node histogram (native int LDS atomics)
    for (int i = t; i < stored; i += 512)
        atomicAdd(&ncnt[gkeys[beg + i] >> 17], 1);
    __syncthreads();

    // scan of RB counters
    if (t < RB) sc[t] = ncnt[t];
    __syncthreads();
    for (int off = 1; off < RB; off <<= 1) {
        int v = 0;
        if (t < RB && t >= off) v = sc[t - off];
        __syncthreads();
        if (t < RB) sc[t] += v;
        __syncthreads();
    }
    if (t < RB) {
        nbase[t] = sc[t] - ncnt[t];
        ncur[t]  = sc[t] - ncnt[t];
    }
    __syncthreads();

    // pass 2: scatter (d, w) grouped by local src; weights lane-parallel
    for (int i = t; i < stored; i += 512) {
        int k = gkeys[beg + i];
        int d = k & 0x1FFFF, ls = k >> 17;
        float tmp = fsl[ls] + f_dst[d];
        float w = __expf(-((tmp > 0.f) ? tmp : ALPHA * tmp));
        int pos = atomicAdd(&ncur[ls], 1);
        sdw[pos] = make_int2(d, __float_as_int(w));
    }
    __syncthreads();

    // pass 3: wave-per-node, two edges per iteration (32-lane halves)
    const int lane = t & 63, wid = t >> 6;
    const int cl = (lane & 31) * 4;          // 4 cols per lane within half
    const bool isB = lane >= 32;
    for (int ni = wid; ni < nn; ni += 8) {
        const int jb = nbase[ni];
        const int cn = ncnt[ni];
        const int halfA = (cn + 1) >> 1;
        const int halfB = cn - halfA;
        const int lim = isB ? halfB : halfA;
        const int jbh = jb + (isB ? halfA : 0);
        float a0 = 0.f, a1 = 0.f, a2 = 0.f, a3 = 0.f, rowsum = 0.f;
        #pragma unroll 4
        for (int it = 0; it < halfA; ++it) {
            bool valid = it < lim;
            int2 dw = sdw[valid ? (jbh + it) : jb];
            float w = valid ? __int_as_float(dw.y) : 0.f;
            ushort4 hv = *(const ushort4*)&hb[(size_t)dw.x * D_OUT + cl];
            rowsum += w;
            a0 = fmaf(w, bf2f(hv.x), a0);
            a1 = fmaf(w, bf2f(hv.y), a1);
            a2 = fmaf(w, bf2f(hv.z), a2);
            a3 = fmaf(w, bf2f(hv.w), a3);
        }
        // overflow fallback (only when a bucket exceeded CAPG; ~never)
        if (ovf_n > 0) {
            for (int o = 0; o < ovf_n; ++o) {
                int2 ov = ovf[o];
                if (ov.x == b && (ov.y >> 17) == ni && !isB) {
                    int d = ov.y & 0x1FFFF;
                    float tmp = fsl[ni] + f_dst[d];
                    float w = __expf(-((tmp > 0.f) ? tmp : ALPHA * tmp));
                    ushort4 hv = *(const ushort4*)&hb[(size_t)d * D_OUT + cl];
                    rowsum += w;
                    a0 = fmaf(w, bf2f(hv.x), a0);
                    a1 = fmaf(w, bf2f(hv.y), a1);
                    a2 = fmaf(w, bf2f(hv.z), a2);
                    a3 = fmaf(w, bf2f(hv.w), a3);
                }
            }
        }
        // combine halves
        rowsum += __shfl_xor(rowsum, 32);
        a0 += __shfl_xor(a0, 32);
        a1 += __shfl_xor(a1, 32);
        a2 += __shfl_xor(a2, 32);
        a3 += __shfl_xor(a3, 32);
        if (!isB) {
            float inv = 1.f / rowsum;
            a0 *= inv; a1 *= inv; a2 *= inv; a3 *= inv;
            a0 = (a0 > 0.f) ? a0 : (__expf(a0) - 1.f);
            a1 = (a1 > 0.f) ? a1 : (__expf(a1) - 1.f);
            a2 = (a2 > 0.f) ? a2 : (__expf(a2) - 1.f);
            a3 = (a3 > 0.f) ? a3 : (__expf(a3) - 1.f);
            *(float4*)&out[(size_t)(s0 + ni) * D_OUT + cl] =
                make_float4(a0, a1, a2, a3);
        }
    }
}

extern "C" void kernel_launch(void* const* d_in, const int* in_sizes, int n_in,
                              void* d_out, int out_size, void* d_ws, size_t ws_size,
                              hipStream_t stream) {
    const float* x    = (const float*)d_in[0];
    const int*   edge = (const int*)d_in[1];   // JAX no-x64: int64 -> int32
    const float* W    = (const float*)d_in[2];
    const float* a    = (const float*)d_in[3];
    float* out = (float*)d_out;

    const int n = in_sizes[0] / D_IN;
    const int E = in_sizes[1] / 2;
    const int* src = edge;
    const int* dst = edge + E;
    const int nb = (n + RB - 1) / RB;

    char* p = (char*)d_ws;
    unsigned short* hb  = (unsigned short*)p; p += (size_t)n * D_OUT * sizeof(unsigned short);
    unsigned short* WTb = (unsigned short*)p; p += (size_t)D_OUT * D_IN * sizeof(unsigned short);
    float* f_src = (float*)p;  p += (size_t)n * sizeof(float);
    float* f_dst = (float*)p;  p += (size_t)n * sizeof(float);
    int*  gcnt   = (int*)p;    p += (size_t)(nb + 1) * sizeof(int);
    int2* ovf    = (int2*)p;   p += (size_t)OVFCAP * sizeof(int2);
    int*  gkeys  = (int*)p;    p += (size_t)nb * CAPG * sizeof(int);

    const int gemm_blocks = (n + 127) / 128;

    k_wt<<<D_OUT, 256, 0, stream>>>(W, WTb);
    k_gemm<<<gemm_blocks, 256, 0, stream>>>(x, WTb, a, hb, f_src, f_dst, n);

    hipMemsetAsync(gcnt, 0, (size_t)(nb + 1) * sizeof(int), stream);
    k_bfill<<<(E + CH - 1) / CH, 256, 0, stream>>>(src, dst, gcnt, ovf, gkeys, E, nb);
    k_bagg<<<nb, 512, 0, stream>>>(hb, f_src, f_dst, gcnt, ovf, gkeys, out, n, nb);
}